// Round 13
// baseline (318.915 us; speedup 1.0000x reference)
//
#include <hip/hip_runtime.h>
#include <hip/hip_bf16.h>
#include <stdint.h>

#define B_DIM 4096
#define P_DIMC 1024
#define H_DIMC 2048
#define X_DIMC 1024
#define K_DIM 4096   // P + H + X
#define N_DIM 8192   // 4*H (gate-minor packed: n = (h>>4)*64 + gate*16 + (h&15))

#define BM 256
#define BN 128
#define BK 32
#define NT (K_DIM / BK)   // 128 K-tiles

typedef __attribute__((ext_vector_type(8))) short bf16x8;
typedef __attribute__((ext_vector_type(4))) float f32x4;

template <int V> struct Int { static constexpr int value = V; };

__device__ __forceinline__ unsigned short f2bf(float f) {
  union { float f; unsigned u; } v; v.f = f;
  unsigned u = v.u;
  u += 0x7FFFu + ((u >> 16) & 1u);   // round-to-nearest-even
  return (unsigned short)(u >> 16);
}

__device__ __forceinline__ float sigm(float x) { return 1.f / (1.f + __expf(-x)); }
__device__ __forceinline__ float tanh_fast(float x) {
  float e = __expf(2.f * x);
  return 1.f - 2.f / (e + 1.f);      // safe at +/- inf
}

__device__ __forceinline__ void gl_lds16(const void* g, void* l) {
  __builtin_amdgcn_global_load_lds((const __attribute__((address_space(1))) void*)g,
                                   (__attribute__((address_space(3))) void*)l, 16, 0, 0);
}

// ---------------- pack A = [P | hidden | ext] -> bf16 [B][K] ----------------
__global__ void pack_a_kernel(const float* __restrict__ P, const float* __restrict__ Hd,
                              const float* __restrict__ X, unsigned short* __restrict__ A) {
  const int total = B_DIM * (K_DIM / 4);
  for (int idx = blockIdx.x * blockDim.x + threadIdx.x; idx < total;
       idx += gridDim.x * blockDim.x) {
    int row = idx >> 10;
    int col = (idx & 1023) << 2;
    const float* src; int off;
    if (col < P_DIMC)                { src = P;  off = row * P_DIMC + col; }
    else if (col < P_DIMC + H_DIMC)  { src = Hd; off = row * H_DIMC + (col - P_DIMC); }
    else                             { src = X;  off = row * X_DIMC + (col - P_DIMC - H_DIMC); }
    float4 v = *(const float4*)(src + off);
    ushort4 o;
    o.x = f2bf(v.x); o.y = f2bf(v.y); o.z = f2bf(v.z); o.w = f2bf(v.w);
    *(ushort4*)(A + (size_t)row * K_DIM + col) = o;
  }
}

// ------- pack Wbig [N][K] bf16, gate-minor at 16 granularity ----------------
// row n holds weights for gate=(n>>4)&3, h=((n>>6)<<4)|(n&15)
struct WPtrs {
  const float *pi, *pf, *pg, *po;
  const float *hi, *hf, *hg, *ho;
  const float *xi, *xf, *xg, *xo;
};

__global__ void pack_w_kernel(WPtrs w, unsigned short* __restrict__ Wo) {
  const int total = N_DIM * (K_DIM / 4);
  for (int idx = blockIdx.x * blockDim.x + threadIdx.x; idx < total;
       idx += gridDim.x * blockDim.x) {
    int n = idx >> 10;
    int col = (idx & 1023) << 2;
    int gate = (n >> 4) & 3;
    int h = ((n >> 6) << 4) | (n & 15);
    const float* src; int off;
    if (col < P_DIMC) {
      src = gate == 0 ? w.pi : gate == 1 ? w.pf : gate == 2 ? w.pg : w.po;
      off = h * P_DIMC + col;
    } else if (col < P_DIMC + H_DIMC) {
      src = gate == 0 ? w.hi : gate == 1 ? w.hf : gate == 2 ? w.hg : w.ho;
      off = h * H_DIMC + (col - P_DIMC);
    } else {
      src = gate == 0 ? w.xi : gate == 1 ? w.xf : gate == 2 ? w.xg : w.xo;
      off = h * X_DIMC + (col - P_DIMC - H_DIMC);
    }
    float4 v = *(const float4*)(src + off);
    ushort4 o;
    o.x = f2bf(v.x); o.y = f2bf(v.y); o.z = f2bf(v.z); o.w = f2bf(v.w);
    *(ushort4*)(Wo + (size_t)n * K_DIM + col) = o;
  }
}

// ------ fused GEMM (256x128 tile, R9 schedule, ring-2, 2 blocks/CU) ---------
// 48 KiB LDS + ~115 VGPR (acc=64) => 2 co-resident blocks per CU hide each
// other's vmcnt/barrier stalls (m97/m114 mechanism). Per tile: stage t+1 at
// p0 (3 gl_lds), two SB-fenced phases of 8 MFMA, vmcnt(0)+barrier at end.
__global__ __launch_bounds__(512, 4) void gemm_lstm_kernel(
    const unsigned short* __restrict__ A, const unsigned short* __restrict__ W,
    const float* __restrict__ cell,
    const float* __restrict__ bpi, const float* __restrict__ bpf,
    const float* __restrict__ bpg, const float* __restrict__ bpo,
    float* __restrict__ out) {
  // ring-2: 2 * (256x32 A) = 32 KiB + 2 * (128x32 B) = 16 KiB -> 48 KiB
  __shared__ __align__(16) short As[2][BM * BK];
  __shared__ __align__(16) short Bs[2][BN * BK];

  const int T = threadIdx.x;
  const int wave = T >> 6, lane = T & 63;
  const int wm = wave >> 1, wn = wave & 1;     // 4 x 2 wave grid (64x64 tiles)

  // XCD-aware mapping: 1024 blocks, XCD x gets an 8bm x 16bn patch
  const int x = blockIdx.x & 7, local = blockIdx.x >> 3;   // local 0..127
  const int bm = (x & 1) * 8 + (local >> 4);               // 0..15
  const int bn = (x >> 1) * 16 + (local & 15);             // 0..63

  // ---- staging: linear LDS dest, chunk-rotated global source ----
  // row r (64B = 4 chunks of 16B): logical chunk c stored at slot (c+(r>>1))&3
  const int cg = ((T & 3) - (T >> 3)) & 3;     // logical chunk this thread fetches
  const int rowS = T >> 2;                     // 0..127
  const unsigned short* aG0 = A + (size_t)(bm * BM + rowS) * K_DIM + cg * 8;
  const unsigned short* aG1 = A + (size_t)(bm * BM + 128 + rowS) * K_DIM + cg * 8;
  const unsigned short* bG  = W + (size_t)(bn * BN + rowS) * K_DIM + cg * 8;
  const int dstOff = T * 8;                    // shorts

#define STAGE_TILE(BUF, KT)                                                   \
  gl_lds16(aG0 + (KT), &As[BUF][0] + dstOff);                                 \
  gl_lds16(aG1 + (KT), &As[BUF][4096] + dstOff);                              \
  gl_lds16(bG + (KT), &Bs[BUF][0] + dstOff);

  // ---- fragment read offsets (swizzled; same formula as R9, 0 conflicts) ---
  const int lrow = lane & 15, kgrp = lane >> 4;
  const int slotR = (kgrp + (lrow >> 1)) & 3;
  int offA[4], offB[4];
#pragma unroll
  for (int mf = 0; mf < 4; ++mf) offA[mf] = (wm * 64 + mf * 16 + lrow) * BK + slotR * 8;
#pragma unroll
  for (int nf = 0; nf < 4; ++nf) offB[nf] = (wn * 64 + nf * 16 + lrow) * BK + slotR * 8;

  f32x4 acc[4][4] = {};

  // ---- prologue: stage tile 0, drain, barrier ----
  STAGE_TILE(0, 0)
  asm volatile("s_waitcnt vmcnt(0)" ::: "memory");
  __builtin_amdgcn_s_barrier();

  // K-loop templated on compile-time m-half stagger (F = 0 or 2)
  auto run_loop = [&](auto firstc) {
    constexpr int F = decltype(firstc)::value;
    constexpr int S = 2 - F;
    for (int t = 0; t < NT; ++t) {
      const int cur = t & 1, nxt = cur ^ 1;
      const short* bufA = &As[cur][0];
      const short* bufB = &Bs[cur][0];
      bf16x8 av[2], bv[4];

      // ---- p0: bv + av(F half); stage tile t+1; 8 MFMA ----
#pragma unroll
      for (int j = 0; j < 4; ++j) bv[j] = *(const bf16x8*)(bufB + offB[j]);
#pragma unroll
      for (int i = 0; i < 2; ++i) av[i] = *(const bf16x8*)(bufA + offA[F + i]);
      if (t < NT - 1) { STAGE_TILE(nxt, (t + 1) * BK) }
      __builtin_amdgcn_s_setprio(1);
#pragma unroll
      for (int mi = 0; mi < 2; ++mi)
#pragma unroll
        for (int ni = 0; ni < 4; ++ni)
          acc[F + mi][ni] =
              __builtin_amdgcn_mfma_f32_16x16x32_bf16(av[mi], bv[ni], acc[F + mi][ni], 0, 0, 0);
      __builtin_amdgcn_s_setprio(0);
      __builtin_amdgcn_sched_barrier(0);

      // ---- p1: av(S half); 8 MFMA ----
#pragma unroll
      for (int i = 0; i < 2; ++i) av[i] = *(const bf16x8*)(bufA + offA[S + i]);
      __builtin_amdgcn_s_setprio(1);
#pragma unroll
      for (int mi = 0; mi < 2; ++mi)
#pragma unroll
        for (int ni = 0; ni < 4; ++ni)
          acc[S + mi][ni] =
              __builtin_amdgcn_mfma_f32_16x16x32_bf16(av[mi], bv[ni], acc[S + mi][ni], 0, 0, 0);
      __builtin_amdgcn_s_setprio(0);
      __builtin_amdgcn_sched_barrier(0);

      // ---- tile end: t+1 must be resident (drain hidden by co-resident block)
      if (t < NT - 1) {
        asm volatile("s_waitcnt vmcnt(0)" ::: "memory");
        __builtin_amdgcn_s_barrier();
      }
    }
  };
  if (wave & 1) run_loop(Int<2>{});
  else          run_loop(Int<0>{});

  // ---- fused LSTM epilogue (per-lane: n-frags 0..3 = gates i,f,g,o of h) ---
  const int h = bn * 32 + wn * 16 + lrow;
  const float bi = bpi[h], bf_ = bpf[h], bg = bpg[h], bo = bpo[h];
  const int rbase = bm * BM + wm * 64 + kgrp * 4;
#pragma unroll
  for (int mf = 0; mf < 4; ++mf) {
#pragma unroll
    for (int r = 0; r < 4; ++r) {
      const int brow = rbase + mf * 16 + r;
      float gi = acc[mf][0][r] + bi;
      float gf = acc[mf][1][r] + bf_;
      float gg = acc[mf][2][r] + bg;
      float go = acc[mf][3][r] + bo;
      float i_ = sigm(gi), f_ = sigm(gf), g_ = tanh_fast(gg), o_ = sigm(go);
      float cold = cell[(size_t)brow * H_DIMC + h];
      float cn = f_ * cold + i_ * g_;
      out[(size_t)brow * H_DIMC + h] = o_ * tanh_fast(cn);
      out[(size_t)B_DIM * H_DIMC + (size_t)brow * H_DIMC + h] = cn;
    }
  }
}

extern "C" void kernel_launch(void* const* d_in, const int* in_sizes, int n_in,
                              void* d_out, int out_size, void* d_ws, size_t ws_size,
                              hipStream_t stream) {
  const float* P    = (const float*)d_in[0];
  const float* Hd   = (const float*)d_in[1];
  const float* cell = (const float*)d_in[2];
  const float* X    = (const float*)d_in[3];
  WPtrs w;
  w.pi = (const float*)d_in[4];   const float* bpi = (const float*)d_in[5];
  w.pf = (const float*)d_in[6];   const float* bpf = (const float*)d_in[7];
  w.pg = (const float*)d_in[8];   const float* bpg = (const float*)d_in[9];
  w.po = (const float*)d_in[10];  const float* bpo = (const float*)d_in[11];
  w.hi = (const float*)d_in[12];  w.hf = (const float*)d_in[13];
  w.hg = (const float*)d_in[14];  w.ho = (const float*)d_in[15];
  w.xi = (const float*)d_in[16];  w.xf = (const float*)d_in[17];
  w.xg = (const float*)d_in[18];  w.xo = (const float*)d_in[19];

  unsigned short* Abf = (unsigned short*)d_ws;                 // 32 MiB
  unsigned short* Wbf = Abf + (size_t)B_DIM * K_DIM;           // 64 MiB

  pack_a_kernel<<<2048, 256, 0, stream>>>(P, Hd, X, Abf);
  pack_w_kernel<<<2048, 256, 0, stream>>>(w, Wbf);
  gemm_lstm_kernel<<<1024, 512, 0, stream>>>(Abf, Wbf, cell, bpi, bpf, bpg, bpo,
                                             (float*)d_out);
}

// Round 14
// 296.851 us; speedup vs baseline: 1.0743x; 1.0743x over previous
//
#include <hip/hip_runtime.h>
#include <hip/hip_bf16.h>
#include <stdint.h>

#define B_DIM 4096
#define P_DIMC 1024
#define H_DIMC 2048
#define X_DIMC 1024
#define K_DIM 4096   // P + H + X
#define N_DIM 8192   // 4*H (gate-minor packed: n = (h>>4)*64 + gate*16 + (h&15))

#define BM 256
#define BN 256
#define BK 64
#define NT (K_DIM / BK)   // 64 K-tiles

typedef __attribute__((ext_vector_type(8))) short bf16x8;
typedef __attribute__((ext_vector_type(4))) float f32x4;

template <int V> struct Int { static constexpr int value = V; };

__device__ __forceinline__ unsigned short f2bf(float f) {
  union { float f; unsigned u; } v; v.f = f;
  unsigned u = v.u;
  u += 0x7FFFu + ((u >> 16) & 1u);   // round-to-nearest-even
  return (unsigned short)(u >> 16);
}

__device__ __forceinline__ float sigm(float x) { return 1.f / (1.f + __expf(-x)); }
__device__ __forceinline__ float tanh_fast(float x) {
  float e = __expf(2.f * x);
  return 1.f - 2.f / (e + 1.f);      // safe at +/- inf
}

__device__ __forceinline__ void gl_lds16(const void* g, void* l) {
  __builtin_amdgcn_global_load_lds((const __attribute__((address_space(1))) void*)g,
                                   (__attribute__((address_space(3))) void*)l, 16, 0, 0);
}

struct WPtrs {
  const float *pi, *pf, *pg, *po;
  const float *hi, *hf, *hg, *ho;
  const float *xi, *xf, *xg, *xo;
};

// ------- merged pack: A = [P|hidden|ext] -> bf16 [B][K]  and W -> Wbig ------
// 8-elem vectorized: 2x float4 load (32B), 1x ushort8 store (16B).
// W row n holds gate=(n>>4)&3, h=((n>>6)<<4)|(n&15).
__global__ void pack_kernel(const float* __restrict__ P, const float* __restrict__ Hd,
                            const float* __restrict__ X, WPtrs w,
                            unsigned short* __restrict__ A, unsigned short* __restrict__ Wo) {
  const int NA = B_DIM * (K_DIM / 8);          // 2M chunks of 8
  const int NW = N_DIM * (K_DIM / 8);          // 4M chunks of 8
  for (int idx = blockIdx.x * blockDim.x + threadIdx.x; idx < NA + NW;
       idx += gridDim.x * blockDim.x) {
    const float* src; int off; unsigned short* dst; size_t doff;
    if (idx < NA) {
      int row = idx >> 9;
      int col = (idx & 511) << 3;
      if (col < P_DIMC)                { src = P;  off = row * P_DIMC + col; }
      else if (col < P_DIMC + H_DIMC)  { src = Hd; off = row * H_DIMC + (col - P_DIMC); }
      else                             { src = X;  off = row * X_DIMC + (col - P_DIMC - H_DIMC); }
      dst = A; doff = (size_t)row * K_DIM + col;
    } else {
      int j = idx - NA;
      int n = j >> 9;
      int col = (j & 511) << 3;
      int gate = (n >> 4) & 3;
      int h = ((n >> 6) << 4) | (n & 15);
      if (col < P_DIMC) {
        src = gate == 0 ? w.pi : gate == 1 ? w.pf : gate == 2 ? w.pg : w.po;
        off = h * P_DIMC + col;
      } else if (col < P_DIMC + H_DIMC) {
        src = gate == 0 ? w.hi : gate == 1 ? w.hf : gate == 2 ? w.hg : w.ho;
        off = h * H_DIMC + (col - P_DIMC);
      } else {
        src = gate == 0 ? w.xi : gate == 1 ? w.xf : gate == 2 ? w.xg : w.xo;
        off = h * X_DIMC + (col - P_DIMC - H_DIMC);
      }
      dst = Wo; doff = (size_t)n * K_DIM + col;
    }
    float4 v0 = *(const float4*)(src + off);
    float4 v1 = *(const float4*)(src + off + 4);
    ushort4 o0, o1;
    o0.x = f2bf(v0.x); o0.y = f2bf(v0.y); o0.z = f2bf(v0.z); o0.w = f2bf(v0.w);
    o1.x = f2bf(v1.x); o1.y = f2bf(v1.y); o1.z = f2bf(v1.z); o1.w = f2bf(v1.w);
    union { ushort4 h[2]; uint4 u; } pk;
    pk.h[0] = o0; pk.h[1] = o1;
    *(uint4*)(dst + doff) = pk.u;              // 16B store
  }
}

// ------ fused GEMM (256x256, BK=64, R12 schedule, ring-2, 64 barriers) ------
// Per tile: 4 SB-fenced phases {reads, [stages at p0], 16 MFMA}; all 8 stage
// insts for t+1 issue at p0 (full-tile lead); ONE vmcnt(0) + ONE barrier at
// tile end. No lgkm drains (compiler emits counted waits). 8-chunk rotation
// swizzle for 128B rows (0 conflicts measured).
__global__ __launch_bounds__(512, 1) void gemm_lstm_kernel(
    const unsigned short* __restrict__ A, const unsigned short* __restrict__ W,
    const float* __restrict__ cell,
    const float* __restrict__ bpi, const float* __restrict__ bpf,
    const float* __restrict__ bpg, const float* __restrict__ bpo,
    float* __restrict__ out) {
  // ring-2: 2 * (256x64 A + 256x64 B) * 2B = 128 KiB
  __shared__ __align__(16) short As[2][BM * BK];
  __shared__ __align__(16) short Bs[2][BN * BK];

  const int T = threadIdx.x;
  const int wave = T >> 6, lane = T & 63;
  const int wm = wave >> 2, wn = wave & 3;     // 2 x 4 wave grid

  // XCD-aware mapping: 512 blocks, XCD x gets an 8x8 tile patch
  const int x = blockIdx.x & 7, local = blockIdx.x >> 3;   // local 0..63
  const int bm = (x & 1) * 8 + (local >> 3);               // 0..15
  const int bn = (x >> 1) * 8 + (local & 7);               // 0..31

  // ---- staging: linear LDS dest, chunk-rotated global source ----
  // row r (128B = 8 chunks of 16B): logical chunk c stored at slot (c + (r&7))&7
  const int rowS = T >> 3;                     // 0..63 (call q covers rows q*64+rowS)
  const int cg = ((T & 7) - (rowS & 7)) & 7;   // logical chunk this thread fetches
  const unsigned short* aGq[4];
  const unsigned short* bGq[4];
#pragma unroll
  for (int q = 0; q < 4; ++q) {
    aGq[q] = A + (size_t)(bm * BM + q * 64 + rowS) * K_DIM + cg * 8;
    bGq[q] = W + (size_t)(bn * BN + q * 64 + rowS) * K_DIM + cg * 8;
  }
  const int dstOff = T * 8;                    // shorts; call q adds q*4096

#define STAGE_TILE(BUF, KT)                                                   \
  _Pragma("unroll") for (int q = 0; q < 4; ++q)                               \
    gl_lds16(aGq[q] + (KT), &As[BUF][q * 4096] + dstOff);                     \
  _Pragma("unroll") for (int q = 0; q < 4; ++q)                               \
    gl_lds16(bGq[q] + (KT), &Bs[BUF][q * 4096] + dstOff);

  // ---- fragment read offsets (swizzled; chunk c = ks*4 + kgrp) ----
  const int lrow = lane & 15, kgrp = lane >> 4;
  int offA[8][2], offB[4][2];
#pragma unroll
  for (int mf = 0; mf < 8; ++mf)
#pragma unroll
    for (int ks = 0; ks < 2; ++ks)
      offA[mf][ks] = (wm * 128 + mf * 16 + lrow) * BK +
                     (((ks * 4 + kgrp) + (lrow & 7)) & 7) * 8;
#pragma unroll
  for (int nf = 0; nf < 4; ++nf)
#pragma unroll
    for (int ks = 0; ks < 2; ++ks)
      offB[nf][ks] = (wn * 64 + nf * 16 + lrow) * BK +
                     (((ks * 4 + kgrp) + (lrow & 7)) & 7) * 8;

  f32x4 acc[8][4] = {};

  // ---- prologue: stage tile 0, drain, barrier ----
  STAGE_TILE(0, 0)
  asm volatile("s_waitcnt vmcnt(0)" ::: "memory");
  __builtin_amdgcn_s_barrier();

  // K-loop templated on compile-time A-half stagger (FIRST = 0 or 4)
  auto run_loop = [&](auto firstc) {
    constexpr int F = decltype(firstc)::value;
    constexpr int S = 4 - F;
    for (int t = 0; t < NT; ++t) {
      const int cur = t & 1, nxt = cur ^ 1;
      const short* bufA = &As[cur][0];
      const short* bufB = &Bs[cur][0];
      bf16x8 av[4], bv[4];

      // ---- p0: bv(ks0) + av(F half, ks0); stage ALL of tile t+1; MFMA ----
#pragma unroll
      for (int j = 0; j < 4; ++j) bv[j] = *(const bf16x8*)(bufB + offB[j][0]);
#pragma unroll
      for (int i = 0; i < 4; ++i) av[i] = *(const bf16x8*)(bufA + offA[F + i][0]);
      if (t < NT - 1) { STAGE_TILE(nxt, (t + 1) * BK) }
      __builtin_amdgcn_s_setprio(1);
#pragma unroll
      for (int mi = 0; mi < 4; ++mi)
#pragma unroll
        for (int ni = 0; ni < 4; ++ni)
          acc[F + mi][ni] =
              __builtin_amdgcn_mfma_f32_16x16x32_bf16(av[mi], bv[ni], acc[F + mi][ni], 0, 0, 0);
      __builtin_amdgcn_s_setprio(0);
      __builtin_amdgcn_sched_barrier(0);

      // ---- p1: av(S half, ks0); MFMA ----
#pragma unroll
      for (int i = 0; i < 4; ++i) av[i] = *(const bf16x8*)(bufA + offA[S + i][0]);
      __builtin_amdgcn_s_setprio(1);
#pragma unroll
      for (int mi = 0; mi < 4; ++mi)
#pragma unroll
        for (int ni = 0; ni < 4; ++ni)
          acc[S + mi][ni] =
              __builtin_amdgcn_mfma_f32_16x16x32_bf16(av[mi], bv[ni], acc[S + mi][ni], 0, 0, 0);
      __builtin_amdgcn_s_setprio(0);
      __builtin_amdgcn_sched_barrier(0);

      // ---- p2: bv(ks1) + av(F half, ks1); MFMA ----
#pragma unroll
      for (int j = 0; j < 4; ++j) bv[j] = *(const bf16x8*)(bufB + offB[j][1]);
#pragma unroll
      for (int i = 0; i < 4; ++i) av[i] = *(const bf16x8*)(bufA + offA[F + i][1]);
      __builtin_amdgcn_s_setprio(1);
#pragma unroll
      for (int mi = 0; mi < 4; ++mi)
#pragma unroll
        for (int ni = 0; ni < 4; ++ni)
          acc[F + mi][ni] =
              __builtin_amdgcn_mfma_f32_16x16x32_bf16(av[mi], bv[ni], acc[F + mi][ni], 0, 0, 0);
      __builtin_amdgcn_s_setprio(0);
      __builtin_amdgcn_sched_barrier(0);

      // ---- p3: av(S half, ks1); MFMA ----
#pragma unroll
      for (int i = 0; i < 4; ++i) av[i] = *(const bf16x8*)(bufA + offA[S + i][1]);
      __builtin_amdgcn_s_setprio(1);
#pragma unroll
      for (int mi = 0; mi < 4; ++mi)
#pragma unroll
        for (int ni = 0; ni < 4; ++ni)
          acc[S + mi][ni] =
              __builtin_amdgcn_mfma_f32_16x16x32_bf16(av[mi], bv[ni], acc[S + mi][ni], 0, 0, 0);
      __builtin_amdgcn_s_setprio(0);
      __builtin_amdgcn_sched_barrier(0);

      // ---- tile end: t+1 (issued at p0, ~3 phases ago) must be resident ----
      if (t < NT - 1) {
        asm volatile("s_waitcnt vmcnt(0)" ::: "memory");
        __builtin_amdgcn_s_barrier();
      }
    }
  };
  if (wave & 1) run_loop(Int<4>{});
  else          run_loop(Int<0>{});

  // ---- fused LSTM epilogue (per-lane: n-frags 0..3 = gates i,f,g,o of h) ---
  const int h = bn * 64 + wn * 16 + lrow;
  const float bi = bpi[h], bf_ = bpf[h], bg = bpg[h], bo = bpo[h];
  const int rbase = bm * BM + wm * 128 + kgrp * 4;
#pragma unroll
  for (int mf = 0; mf < 8; ++mf) {
#pragma unroll
    for (int r = 0; r < 4; ++r) {
      const int brow = rbase + mf * 16 + r;
      float gi = acc[mf][0][r] + bi;
      float gf = acc[mf][1][r] + bf_;
      float gg = acc[mf][2][r] + bg;
      float go = acc[mf][3][r] + bo;
      float i_ = sigm(gi), f_ = sigm(gf), g_ = tanh_fast(gg), o_ = sigm(go);
      float cold = cell[(size_t)brow * H_DIMC + h];
      float cn = f_ * cold + i_ * g_;
      out[(size_t)brow * H_DIMC + h] = o_ * tanh_fast(cn);
      out[(size_t)B_DIM * H_DIMC + (size_t)brow * H_DIMC + h] = cn;
    }
  }
}

extern "C" void kernel_launch(void* const* d_in, const int* in_sizes, int n_in,
                              void* d_out, int out_size, void* d_ws, size_t ws_size,
                              hipStream_t stream) {
  const float* P    = (const float*)d_in[0];
  const float* Hd   = (const float*)d_in[1];
  const float* cell = (const float*)d_in[2];
  const float* X    = (const float*)d_in[3];
  WPtrs w;
  w.pi = (const float*)d_in[4];   const float* bpi = (const float*)d_in[5];
  w.pf = (const float*)d_in[6];   const float* bpf = (const float*)d_in[7];
  w.pg = (const float*)d_in[8];   const float* bpg = (const float*)d_in[9];
  w.po = (const float*)d_in[10];  const float* bpo = (const float*)d_in[11];
  w.hi = (const float*)d_in[12];  w.hf = (const float*)d_in[13];
  w.hg = (const float*)d_in[14];  w.ho = (const float*)d_in[15];
  w.xi = (const float*)d_in[16];  w.xf = (const float*)d_in[17];
  w.xg = (const float*)d_in[18];  w.xo = (const float*)d_in[19];

  unsigned short* Abf = (unsigned short*)d_ws;                 // 32 MiB
  unsigned short* Wbf = Abf + (size_t)B_DIM * K_DIM;           // 64 MiB

  pack_kernel<<<2048, 256, 0, stream>>>(P, Hd, X, w, Abf, Wbf);
  gemm_lstm_kernel<<<512, 512, 0, stream>>>(Abf, Wbf, cell, bpi, bpf, bpg, bpo,
                                            (float*)d_out);
}